// Round 3
// baseline (134.799 us; speedup 1.0000x reference)
//
#include <hip/hip_runtime.h>

// MSDeformAttn sampling-weight scatter (RankDetr), bug-compatible with the
// reference's axis-mislabeled reshape: output column q' = m/48, m=(l*8+h)*300+q.
//
// R3 = RETRY of the R2 DIAGNOSTIC (R2 died to an infra "container failed
// twice" acquisition error; source was R0-identical + a 4x launch loop, so
// the code is not implicated). Kernel body is the exact R0 best (79.7us).
// kernel_launch fires it 4x back-to-back: every output element is written
// exactly once per launch (no global RMW), so repeats are bit-identical and
// graph-capture-safe. dur_us - 80.6 = 3 * T_kernel isolates the kernel's
// standalone time from the harness's fixed ~43us/iter 256MiB poison-fill
// floor that rocprof's top-5 shows. Decision (pre-committed):
//   T_kernel > 12us -> algorithmic rework (merge small-level tiles / QW=16
//                      to cut the 5x redundant per-level scan / skip-zero);
//   8-12us          -> one targeted micro-opt, then stop;
//   T_kernel < 8us  -> harness floor dominates, declare roofline.
//
// Gather-style privatization. Output (S=22223, Q=300) tiled as (level-aligned
// row tiles) x (8-wide q' groups). One block per tile: zero LDS (float4) ->
// scan the q-group's samples for the tile's level, filter by tile rows,
// LDS-atomic the 4 bilinear corners -> coalesced write-out. Output written
// exactly once, no memset needed.
//
// Occupancy: LDS = 8*1280*4 = 40960 B exactly => 4 blocks/CU (4*40 KiB =
// 160 KiB pool), 4 x 8 waves = 32 waves/CU (max). __launch_bounds__(512,8)
// caps VGPRs at 64. Grid 38*21 = 798 <= 1024 resident slots.
//
// Static shapes: N=1, L=6, Q=300, H=8, Lv=4, P=4; TOT=230400 samples.
// spatial: (100,167),(50,84),(25,42),(13,21); lsi = 0,16700,20900,21950.

constexpr int NQ   = 300;
constexpr int QW   = 8;                  // q'-group width
constexpr int NG   = 38;                 // ceil(300/8)
constexpr int NTILES = 21;               // 15 (L0,R=7) + 4 (L1,R=15) + 1 (L2) + 1 (L3)
constexpr int MAXC = 1280;               // cells cap: L0 7*167=1169, L1 15*84=1260, L2 1050
constexpr int BLK  = 512;

__global__ __launch_bounds__(BLK, 8)
void msda_tiled(const float4* __restrict__ loc4,  // sampling_locations as float4 (2 samples each)
                const float4* __restrict__ aw4,   // attention_weights as float4 (4 samples each)
                float*        __restrict__ out) { // (S, NQ)
    __shared__ float sm[QW * MAXC];               // 40,960 B, ql-major

    const int b  = blockIdx.x;
    const int g  = b / NTILES;                    // q'-group 0..37
    const int tb = b % NTILES;                    // s-tile id

    int lv, r0t, nr;
    if (tb < 15)      { lv = 0; r0t = 7  * tb;        nr = min(7,  100 - r0t); }
    else if (tb < 19) { lv = 1; r0t = 15 * (tb - 15); nr = min(15, 50  - r0t); }
    else if (tb < 20) { lv = 2; r0t = 0;              nr = 25; }
    else              { lv = 3; r0t = 0;              nr = 13; }

    const int Wlv_[4] = {167, 84, 42, 21};
    const int Hlv_[4] = {100, 50, 25, 13};
    const int lsi_[4] = {0, 16700, 20900, 21950};
    const int W    = Wlv_[lv];
    const int base = lsi_[lv];
    const int g0   = g * QW;
    const int qw   = min(QW, NQ - g0);            // 8, or 4 for the last group
    const int cells = nr * W;
    const int tid  = threadIdx.x;

    // zero the used LDS rows (qw full rows), float4 stores
    {
        const int nz = qw * (MAXC / 4);
        float4* sm4 = (float4*)sm;
        for (int i = tid; i < nz; i += BLK) sm4[i] = make_float4(0.f, 0.f, 0.f, 0.f);
    }
    __syncthreads();

    // scan: one thread per mi; mi in [0, 48*qw). m = 48*g0 + mi.
    // Sample flat index t = 16*m + 4*lv + p; the 4 p-samples are contiguous.
    const int nm  = 48 * qw;                      // 384 (192 last group)
    const int rlo = r0t, rhi = r0t + nr;
    const float fW = (float)W, fH = (float)Hlv_[lv];

    if (tid < nm) {
        const int mi = tid;
        const int m  = 48 * g0 + mi;
        const int ql = mi / 48;                   // local q' index in [0, qw)
        const int l  = m / 2400;
        const int rem = m - l * 2400;
        const int h  = rem / 300;
        const int q  = rem - h * 300;
        const int t  = (((l * 300 + q) * 8 + h) * 4 + lv) * 4;   // p=0 base

        // vector loads: loc[t..t+3] = 2x float4, aw[t..t+3] = 1x float4
        const float4 xy01 = loc4[(t >> 1) + 0];   // (x0,y0,x1,y1)
        const float4 xy23 = loc4[(t >> 1) + 1];   // (x2,y2,x3,y3)
        const float4 w4   = aw4[t >> 2];

        float* smq = &sm[ql * MAXC];

        #pragma unroll
        for (int p = 0; p < 4; ++p) {
            const float x = (p == 0) ? xy01.x : (p == 1) ? xy01.z : (p == 2) ? xy23.x : xy23.z;
            const float y = (p == 0) ? xy01.y : (p == 1) ? xy01.w : (p == 2) ? xy23.y : xy23.w;
            const float w = (p == 0) ? w4.x   : (p == 1) ? w4.y   : (p == 2) ? w4.z   : w4.w;

            const float cf  = x * fW;
            const float rf  = y * fH;
            const float cfl = floorf(cf), rfl = floorf(rf);
            const float fc  = cf - cfl, fr = rf - rfl;
            const int c0 = (int)cfl, rr = (int)rfl;
            const int c1 = c0 + 1, r1 = rr + 1;

            const bool cv0 = (unsigned)c0 < (unsigned)W;   // 0 <= c0 < W
            const bool cv1 = (unsigned)c1 < (unsigned)W;
            const bool rv0 = (rr >= rlo) & (rr < rhi);     // in-tile (implies 0<=r<H)
            const bool rv1 = (r1 >= rlo) & (r1 < rhi);

            const float omfc = 1.0f - fc, omfr = 1.0f - fr;
            if (rv0) {
                const int ro = (rr - rlo) * W;
                if (cv0) atomicAdd(&smq[ro + c0], w * omfc * omfr);
                if (cv1) atomicAdd(&smq[ro + c1], w * fc   * omfr);
            }
            if (rv1) {
                const int ro = (r1 - rlo) * W;
                if (cv0) atomicAdd(&smq[ro + c0], w * omfc * fr);
                if (cv1) atomicAdd(&smq[ro + c1], w * fc   * fr);
            }
        }
    }
    __syncthreads();

    // write-out: s in [base + r0t*W, +cells), q' in [g0, g0+qw).
    // One float4 global store per (cell, v); LDS gathers are 2 lanes/bank (free).
    const int s0  = base + r0t * W;
    const int nq4 = qw >> 2;                      // 2 (or 1 last group)
    for (int i = tid; i < cells * nq4; i += BLK) {
        const int cell = i / nq4;
        const int v    = i - cell * nq4;
        float4 val;
        val.x = sm[(v * 4 + 0) * MAXC + cell];
        val.y = sm[(v * 4 + 1) * MAXC + cell];
        val.z = sm[(v * 4 + 2) * MAXC + cell];
        val.w = sm[(v * 4 + 3) * MAXC + cell];
        *(float4*)&out[(s0 + cell) * NQ + g0 + v * 4] = val;
    }
}

extern "C" void kernel_launch(void* const* d_in, const int* in_sizes, int n_in,
                              void* d_out, int out_size, void* d_ws, size_t ws_size,
                              hipStream_t stream) {
    const float4* loc4 = (const float4*)d_in[0];  // sampling_locations (fp32), 16B-aligned
    const float4* aw4  = (const float4*)d_in[1];  // attention_weights  (fp32), 16B-aligned
    float* out = (float*)d_out;

    // Diagnostic: 4 identical launches. Output written exactly once per
    // launch (no global RMW) -> bit-identical result; serialized on stream.
    // dur_us - dur_us(R0) = 3 * T_kernel.
    for (int rep = 0; rep < 4; ++rep)
        msda_tiled<<<NG * NTILES, BLK, 0, stream>>>(loc4, aw4, out);
}

// Round 4
// 101.121 us; speedup vs baseline: 1.3330x; 1.3330x over previous
//
#include <hip/hip_runtime.h>

// MSDeformAttn sampling-weight scatter (RankDetr), bug-compatible with the
// reference's axis-mislabeled reshape: output column q' = m/48, m=(l*8+h)*300+q.
//
// R4: exact R0-best kernel + NON-TEMPORAL OUTPUT STORES.
// R3 diagnostic (4x launch) measured T_kernel ~= 18us vs ~62us fixed harness
// floor. Bottom-up cost of the kernel is 7-9us; the gap matches L2
// write-allocate RMW on the output: each block stores only 32B (8 q' x 4B)
// per 1200B output row, so every partial-line store allocate-fetches the
// line from HBM (26.7MB out -> 53-107MB RMW fetch, cold caches after the
// harness's 256MiB poison fill). Output is write-only and never re-read:
// __builtin_nontemporal_store (gfx950 'nt') bypasses allocation, streaming
// byte-masked writes straight out. Bitwise-identical result.
// Predicted: T_kernel 18 -> ~8-10us, dur 80.6 -> ~70-73us. If neutral, the
// RMW theory is dead -> two-stage workspace assembly next.
//
// Gather-style privatization. Output (S=22223, Q=300) tiled as (level-aligned
// row tiles) x (8-wide q' groups). One block per tile: zero LDS (float4) ->
// scan the q-group's samples for the tile's level, filter by tile rows,
// LDS-atomic the 4 bilinear corners -> coalesced write-out. Output written
// exactly once, no memset needed.
//
// Occupancy: LDS = 8*1280*4 = 40960 B exactly => 4 blocks/CU (4*40 KiB =
// 160 KiB pool), 4 x 8 waves = 32 waves/CU (max). __launch_bounds__(512,8)
// caps VGPRs at 64. Grid 38*21 = 798 <= 1024 resident slots.
//
// Static shapes: N=1, L=6, Q=300, H=8, Lv=4, P=4; TOT=230400 samples.
// spatial: (100,167),(50,84),(25,42),(13,21); lsi = 0,16700,20900,21950.

constexpr int NQ   = 300;
constexpr int QW   = 8;                  // q'-group width
constexpr int NG   = 38;                 // ceil(300/8)
constexpr int NTILES = 21;               // 15 (L0,R=7) + 4 (L1,R=15) + 1 (L2) + 1 (L3)
constexpr int MAXC = 1280;               // cells cap: L0 7*167=1169, L1 15*84=1260, L2 1050
constexpr int BLK  = 512;

typedef float v4f __attribute__((ext_vector_type(4)));

__global__ __launch_bounds__(BLK, 8)
void msda_tiled(const float4* __restrict__ loc4,  // sampling_locations as float4 (2 samples each)
                const float4* __restrict__ aw4,   // attention_weights as float4 (4 samples each)
                float*        __restrict__ out) { // (S, NQ)
    __shared__ float sm[QW * MAXC];               // 40,960 B, ql-major

    const int b  = blockIdx.x;
    const int g  = b / NTILES;                    // q'-group 0..37
    const int tb = b % NTILES;                    // s-tile id

    int lv, r0t, nr;
    if (tb < 15)      { lv = 0; r0t = 7  * tb;        nr = min(7,  100 - r0t); }
    else if (tb < 19) { lv = 1; r0t = 15 * (tb - 15); nr = min(15, 50  - r0t); }
    else if (tb < 20) { lv = 2; r0t = 0;              nr = 25; }
    else              { lv = 3; r0t = 0;              nr = 13; }

    const int Wlv_[4] = {167, 84, 42, 21};
    const int Hlv_[4] = {100, 50, 25, 13};
    const int lsi_[4] = {0, 16700, 20900, 21950};
    const int W    = Wlv_[lv];
    const int base = lsi_[lv];
    const int g0   = g * QW;
    const int qw   = min(QW, NQ - g0);            // 8, or 4 for the last group
    const int cells = nr * W;
    const int tid  = threadIdx.x;

    // zero the used LDS rows (qw full rows), float4 stores
    {
        const int nz = qw * (MAXC / 4);
        float4* sm4 = (float4*)sm;
        for (int i = tid; i < nz; i += BLK) sm4[i] = make_float4(0.f, 0.f, 0.f, 0.f);
    }
    __syncthreads();

    // scan: one thread per mi; mi in [0, 48*qw). m = 48*g0 + mi.
    // Sample flat index t = 16*m + 4*lv + p; the 4 p-samples are contiguous.
    const int nm  = 48 * qw;                      // 384 (192 last group)
    const int rlo = r0t, rhi = r0t + nr;
    const float fW = (float)W, fH = (float)Hlv_[lv];

    if (tid < nm) {
        const int mi = tid;
        const int m  = 48 * g0 + mi;
        const int ql = mi / 48;                   // local q' index in [0, qw)
        const int l  = m / 2400;
        const int rem = m - l * 2400;
        const int h  = rem / 300;
        const int q  = rem - h * 300;
        const int t  = (((l * 300 + q) * 8 + h) * 4 + lv) * 4;   // p=0 base

        // vector loads: loc[t..t+3] = 2x float4, aw[t..t+3] = 1x float4
        const float4 xy01 = loc4[(t >> 1) + 0];   // (x0,y0,x1,y1)
        const float4 xy23 = loc4[(t >> 1) + 1];   // (x2,y2,x3,y3)
        const float4 w4   = aw4[t >> 2];

        float* smq = &sm[ql * MAXC];

        #pragma unroll
        for (int p = 0; p < 4; ++p) {
            const float x = (p == 0) ? xy01.x : (p == 1) ? xy01.z : (p == 2) ? xy23.x : xy23.z;
            const float y = (p == 0) ? xy01.y : (p == 1) ? xy01.w : (p == 2) ? xy23.y : xy23.w;
            const float w = (p == 0) ? w4.x   : (p == 1) ? w4.y   : (p == 2) ? w4.z   : w4.w;

            const float cf  = x * fW;
            const float rf  = y * fH;
            const float cfl = floorf(cf), rfl = floorf(rf);
            const float fc  = cf - cfl, fr = rf - rfl;
            const int c0 = (int)cfl, rr = (int)rfl;
            const int c1 = c0 + 1, r1 = rr + 1;

            const bool cv0 = (unsigned)c0 < (unsigned)W;   // 0 <= c0 < W
            const bool cv1 = (unsigned)c1 < (unsigned)W;
            const bool rv0 = (rr >= rlo) & (rr < rhi);     // in-tile (implies 0<=r<H)
            const bool rv1 = (r1 >= rlo) & (r1 < rhi);

            const float omfc = 1.0f - fc, omfr = 1.0f - fr;
            if (rv0) {
                const int ro = (rr - rlo) * W;
                if (cv0) atomicAdd(&smq[ro + c0], w * omfc * omfr);
                if (cv1) atomicAdd(&smq[ro + c1], w * fc   * omfr);
            }
            if (rv1) {
                const int ro = (r1 - rlo) * W;
                if (cv0) atomicAdd(&smq[ro + c0], w * omfc * fr);
                if (cv1) atomicAdd(&smq[ro + c1], w * fc   * fr);
            }
        }
    }
    __syncthreads();

    // write-out: s in [base + r0t*W, +cells), q' in [g0, g0+qw).
    // NON-TEMPORAL float4 stores: output is write-only, partial-line (32B of
    // each 1200B row per block) -> 'nt' skips L2 write-allocate, killing the
    // RMW fetch of the cold output. LDS gathers are 2 lanes/bank (free).
    const int s0  = base + r0t * W;
    const int nq4 = qw >> 2;                      // 2 (or 1 last group)
    for (int i = tid; i < cells * nq4; i += BLK) {
        const int cell = i / nq4;
        const int v    = i - cell * nq4;
        v4f val;
        val.x = sm[(v * 4 + 0) * MAXC + cell];
        val.y = sm[(v * 4 + 1) * MAXC + cell];
        val.z = sm[(v * 4 + 2) * MAXC + cell];
        val.w = sm[(v * 4 + 3) * MAXC + cell];
        __builtin_nontemporal_store(val, (v4f*)&out[(s0 + cell) * NQ + g0 + v * 4]);
    }
}

extern "C" void kernel_launch(void* const* d_in, const int* in_sizes, int n_in,
                              void* d_out, int out_size, void* d_ws, size_t ws_size,
                              hipStream_t stream) {
    const float4* loc4 = (const float4*)d_in[0];  // sampling_locations (fp32), 16B-aligned
    const float4* aw4  = (const float4*)d_in[1];  // attention_weights  (fp32), 16B-aligned
    float* out = (float*)d_out;

    msda_tiled<<<NG * NTILES, BLK, 0, stream>>>(loc4, aw4, out);
}